// Round 13
// baseline (68.862 us; speedup 1.0000x reference)
//
#include <hip/hip_runtime.h>

// LightPrompt inner_structure_update (dense form), MI355X gfx950.
// Outputs (f32, concat): x[4096,128] | adj[4096,4096] | edge_attr[4096,4096,4]
// Store floor ~49us (337.6 MB @ ~6.9 TB/s fill rate).
//
// R13 = R12 (66.6us) with ONE lever: plain stores instead of nontemporal.
// Rationale: rocclr fillBuffer hits 6.9 TB/s with PLAIN stores on this exact
// buffer; we measure 5.07 TB/s effective with NT and have never A/B'd the
// flag. NT (no-allocate) bypasses L2 write-combining; for a 337MB stream
// that ends in HBM either way, L2-buffered writes may schedule better at the
// memory controller. All other structure identical to R12: split-bf16 3-term
// MFMA dot (absmax 2.4e-4 vs 1.23e-2 thr), adj routed through LDS transpose
// for full-line stores, attr direct full-line, x-copy fused.

typedef float  f32x4  __attribute__((ext_vector_type(4)));
typedef short  bf16x8 __attribute__((ext_vector_type(8)));
typedef unsigned short u16x4 __attribute__((ext_vector_type(4)));

static constexpr int Tn = 4096;
static constexpr int Dm = 128;
static constexpr int En = 4;
static constexpr float THRE = 0.55f;
static constexpr float SLOPE = 0.01f;

#define BM 128   // block rows (i)
#define BN 64    // block cols (j)
#define KS 32    // k chunk
#define LDH 40   // u16 per staging row: 80B stride (16B-aligned), 2-way banks
#define LDS_D 68 // f32 per Ds row: 272B stride (16B-aligned); writes 2-way,
                 // b128 reads at the 8-touch/bank minimum (audited)

__device__ __forceinline__ unsigned short bf16rn(float x) {
    unsigned int u = __float_as_uint(x);
    return (unsigned short)((u + 0x7FFFu + ((u >> 16) & 1u)) >> 16);
}
__device__ __forceinline__ float bf16tof(unsigned short h) {
    return __uint_as_float(((unsigned int)h) << 16);
}

__global__ __launch_bounds__(256) void lp_fused(const float* __restrict__ tokens,
                                                const float* __restrict__ edge_token,
                                                float* __restrict__ out) {
    // 34816 B shared: staging arrays (30720 B) alias the front; Ds reuses all
    // of it after the k-loop's final barrier (staging is dead by then).
    __shared__ __align__(16) float smem_f[BM * LDS_D];
    unsigned short* Ah = (unsigned short*)smem_f;     // [BM*LDH]
    unsigned short* Al = Ah + BM * LDH;               // [BM*LDH]
    unsigned short* Bh = Al + BM * LDH;               // [BN*LDH]
    unsigned short* Bl = Bh + BN * LDH;               // [BN*LDH]
    float* Ds = smem_f;                               // [BM][LDS_D]

    const int tid = threadIdx.x;
    const int i0 = blockIdx.y * BM;
    const int j0 = blockIdx.x * BN;

    // x output = tokens verbatim (131072 float4): first 512 of 2048 blocks.
    const int bid = blockIdx.y * (Tn / BN) + blockIdx.x;
    if (bid < 512) {
        reinterpret_cast<f32x4*>(out)[bid * 256 + tid] =
            reinterpret_cast<const f32x4*>(tokens)[bid * 256 + tid];
    }

    const int lane = tid & 63;
    const int w    = tid >> 6;   // wave 0..3
    const int wr   = w >> 1;     // row half (64 rows)
    const int wc   = w & 1;      // col half (32 cols)
    const int lr   = lane & 15;  // frag row/col within 16x16 tile
    const int lk   = lane >> 4;  // k quarter (8 bf16)

    f32x4 acc[4][2];
#pragma unroll
    for (int rt = 0; rt < 4; ++rt)
#pragma unroll
        for (int ct = 0; ct < 2; ++ct) acc[rt][ct] = (f32x4)(0.0f);

#pragma unroll 1
    for (int kp = 0; kp < Dm / KS; ++kp) {
        const int kbase = kp * KS;
        // Stage A (128x32 f32 -> hi/lo bf16): 4 f32x4/thread, 8 lanes/row.
#pragma unroll
        for (int p = 0; p < 4; ++p) {
            const int f = (p << 8) + tid;
            const int row = f >> 3;
            const int c4 = (f & 7) << 2;
            const f32x4 v = *reinterpret_cast<const f32x4*>(
                tokens + (size_t)(i0 + row) * Dm + kbase + c4);
            u16x4 hi, lo;
#pragma unroll
            for (int e = 0; e < 4; ++e) {
                const unsigned short h = bf16rn(v[e]);
                hi[e] = h;
                lo[e] = bf16rn(v[e] - bf16tof(h));
            }
            *reinterpret_cast<u16x4*>(&Ah[row * LDH + c4]) = hi;
            *reinterpret_cast<u16x4*>(&Al[row * LDH + c4]) = lo;
        }
        // Stage B (64x32): 2 f32x4/thread.
#pragma unroll
        for (int p = 0; p < 2; ++p) {
            const int f = (p << 8) + tid;
            const int row = f >> 3;
            const int c4 = (f & 7) << 2;
            const f32x4 v = *reinterpret_cast<const f32x4*>(
                tokens + (size_t)(j0 + row) * Dm + kbase + c4);
            u16x4 hi, lo;
#pragma unroll
            for (int e = 0; e < 4; ++e) {
                const unsigned short h = bf16rn(v[e]);
                hi[e] = h;
                lo[e] = bf16rn(v[e] - bf16tof(h));
            }
            *reinterpret_cast<u16x4*>(&Bh[row * LDH + c4]) = hi;
            *reinterpret_cast<u16x4*>(&Bl[row * LDH + c4]) = lo;
        }
        __syncthreads();

        // Fragments: lane lr = tile row/col, lk*8 = k offset (16B b128 reads).
        bf16x8 afh[4], afl[4], bfh[2], bfl[2];
#pragma unroll
        for (int rt = 0; rt < 4; ++rt) {
            const int row = (wr << 6) + (rt << 4) + lr;
            afh[rt] = *reinterpret_cast<const bf16x8*>(&Ah[row * LDH + (lk << 3)]);
            afl[rt] = *reinterpret_cast<const bf16x8*>(&Al[row * LDH + (lk << 3)]);
        }
#pragma unroll
        for (int ct = 0; ct < 2; ++ct) {
            const int col = (wc << 5) + (ct << 4) + lr;
            bfh[ct] = *reinterpret_cast<const bf16x8*>(&Bh[col * LDH + (lk << 3)]);
            bfl[ct] = *reinterpret_cast<const bf16x8*>(&Bl[col * LDH + (lk << 3)]);
        }
#pragma unroll
        for (int rt = 0; rt < 4; ++rt)
#pragma unroll
            for (int ct = 0; ct < 2; ++ct) {
                acc[rt][ct] = __builtin_amdgcn_mfma_f32_16x16x32_bf16(
                    afh[rt], bfh[ct], acc[rt][ct], 0, 0, 0);
                acc[rt][ct] = __builtin_amdgcn_mfma_f32_16x16x32_bf16(
                    afh[rt], bfl[ct], acc[rt][ct], 0, 0, 0);
                acc[rt][ct] = __builtin_amdgcn_mfma_f32_16x16x32_bf16(
                    afl[rt], bfh[ct], acc[rt][ct], 0, 0, 0);
            }
        __syncthreads();   // also makes staging LDS dead -> Ds reuse safe
    }

    const float e0 = edge_token[0];
    const float e1 = edge_token[1];
    const float e2 = edge_token[2];
    const float e3 = edge_token[3];

    float* __restrict__ adj  = out + (size_t)Tn * Dm;
    float* __restrict__ attr = adj + (size_t)Tn * Tn;

    // C/D layout (m89-verified): col = lane&15, row = (lane>>4)*4 + reg.
    // attr stored direct (4x256B full-line segments per instr); sim*m staged
    // into Ds for the adj transpose.
#pragma unroll
    for (int rt = 0; rt < 4; ++rt) {
#pragma unroll
        for (int ct = 0; ct < 2; ++ct) {
            const f32x4 dv = acc[rt][ct];
            const int jl = (wc << 5) + (ct << 4) + lr;
            const int j = j0 + jl;
#pragma unroll
            for (int reg = 0; reg < 4; ++reg) {
                const int il = (wr << 6) + (rt << 4) + (lk << 2) + reg;
                const float d = dv[reg];
                const float sim = 1.0f / (1.0f + __expf(-d));
                const float m = (sim >= THRE) ? 1.0f : 0.0f;
                Ds[il * LDS_D + jl] = sim * m;
                f32x4 at;
                float v;
                v = d * e0; at.x = (v > 0.0f ? v : SLOPE * v) * m;
                v = d * e1; at.y = (v > 0.0f ? v : SLOPE * v) * m;
                v = d * e2; at.z = (v > 0.0f ? v : SLOPE * v) * m;
                v = d * e3; at.w = (v > 0.0f ? v : SLOPE * v) * m;
                *reinterpret_cast<f32x4*>(attr + ((size_t)(i0 + il) * Tn + j) * En) = at;
            }
        }
    }
    __syncthreads();

    // adj from Ds, row-major: per wave-instr 4 rows x 256B (2 full lines).
    const int c4 = lr << 2;
#pragma unroll
    for (int s = 0; s < 8; ++s) {
        const int row = (w << 5) + (s << 2) + lk;
        const f32x4 v = *reinterpret_cast<const f32x4*>(&Ds[row * LDS_D + c4]);
        *reinterpret_cast<f32x4*>(adj + (size_t)(i0 + row) * Tn + j0 + c4) = v;
    }
}

extern "C" void kernel_launch(void* const* d_in, const int* in_sizes, int n_in,
                              void* d_out, int out_size, void* d_ws, size_t ws_size,
                              hipStream_t stream) {
    const float* tokens     = (const float*)d_in[0];  // [1,4096,128] f32
    const float* edge_token = (const float*)d_in[1];  // [1,4] f32
    float* out = (float*)d_out;

    hipLaunchKernelGGL(lp_fused, dim3(Tn / BN, Tn / BM), dim3(256), 0, stream,
                       tokens, edge_token, out);
}

// Round 14
// 65.697 us; speedup vs baseline: 1.0482x; 1.0482x over previous
//
#include <hip/hip_runtime.h>

// LightPrompt inner_structure_update (dense form), MI355X gfx950.
// Outputs (f32, concat): x[4096,128] | adj[4096,4096] | edge_attr[4096,4096,4]
// Store floor ~49us (337.6 MB @ ~6.9 TB/s fill rate).
//
// R14 = R12 (66.6us, best; NT stores confirmed better than plain by R13's
// A/B: 66.6 vs 68.9) + two levers:
//  - T14 async-STAGE split: issue kp+1's 6 staging loads right after kp's
//    convert consumes the prefetch regs -> L2 latency (~200-400cy) hides
//    under frag reads + 24 MFMA + 2 barriers instead of sitting on the
//    barrier-locked staging critical path. +24 VGPR (live ~120, 4 w/SIMD).
//  - v_rcp_f32 for the sigmoid reciprocal (saves ~8-op div expansion x32;
//    1 ulp ~ 6e-8 on sim, no new mask-flip risk; absmax stays 2.44e-4).
// Structure otherwise identical: split-bf16 3-term MFMA dot (al*bl dropped),
// adj via LDS transpose for full-line NT stores, attr direct NT, x fused.

typedef float  f32x4  __attribute__((ext_vector_type(4)));
typedef short  bf16x8 __attribute__((ext_vector_type(8)));
typedef unsigned short u16x4 __attribute__((ext_vector_type(4)));

static constexpr int Tn = 4096;
static constexpr int Dm = 128;
static constexpr int En = 4;
static constexpr float THRE = 0.55f;
static constexpr float SLOPE = 0.01f;

#define BM 128   // block rows (i)
#define BN 64    // block cols (j)
#define KS 32    // k chunk
#define LDH 40   // u16 per staging row: 80B stride (16B-aligned), 2-way banks
#define LDS_D 68 // f32 per Ds row: 272B stride; writes 2-way, b128 reads min

__device__ __forceinline__ unsigned short bf16rn(float x) {
    unsigned int u = __float_as_uint(x);
    return (unsigned short)((u + 0x7FFFu + ((u >> 16) & 1u)) >> 16);
}
__device__ __forceinline__ float bf16tof(unsigned short h) {
    return __uint_as_float(((unsigned int)h) << 16);
}

__global__ __launch_bounds__(256) void lp_fused(const float* __restrict__ tokens,
                                                const float* __restrict__ edge_token,
                                                float* __restrict__ out) {
    // 34816 B shared: staging arrays (30720 B) alias the front; Ds reuses it
    // after the k-loop's final barrier (staging dead by then).
    __shared__ __align__(16) float smem_f[BM * LDS_D];
    unsigned short* Ah = (unsigned short*)smem_f;     // [BM*LDH]
    unsigned short* Al = Ah + BM * LDH;               // [BM*LDH]
    unsigned short* Bh = Al + BM * LDH;               // [BN*LDH]
    unsigned short* Bl = Bh + BN * LDH;               // [BN*LDH]
    float* Ds = smem_f;                               // [BM][LDS_D]

    const int tid = threadIdx.x;
    const int i0 = blockIdx.y * BM;
    const int j0 = blockIdx.x * BN;

    // x output = tokens verbatim (131072 float4): first 512 of 2048 blocks.
    const int bid = blockIdx.y * (Tn / BN) + blockIdx.x;
    if (bid < 512) {
        reinterpret_cast<f32x4*>(out)[bid * 256 + tid] =
            reinterpret_cast<const f32x4*>(tokens)[bid * 256 + tid];
    }

    const int lane = tid & 63;
    const int w    = tid >> 6;   // wave 0..3
    const int wr   = w >> 1;     // row half (64 rows)
    const int wc   = w & 1;      // col half (32 cols)
    const int lr   = lane & 15;  // frag row/col within 16x16 tile
    const int lk   = lane >> 4;  // k quarter (8 bf16)

    // Per-thread staging coordinates (fixed across kp).
    int arw[4], ac4[4], brw[2], bc4[2];
#pragma unroll
    for (int p = 0; p < 4; ++p) {
        const int f = (p << 8) + tid;
        arw[p] = f >> 3;
        ac4[p] = (f & 7) << 2;
    }
#pragma unroll
    for (int p = 0; p < 2; ++p) {
        const int f = (p << 8) + tid;
        brw[p] = f >> 3;
        bc4[p] = (f & 7) << 2;
    }

    f32x4 acc[4][2];
#pragma unroll
    for (int rt = 0; rt < 4; ++rt)
#pragma unroll
        for (int ct = 0; ct < 2; ++ct) acc[rt][ct] = (f32x4)(0.0f);

    // Prefetch registers: kp's staging data loaded one iteration ahead.
    f32x4 pa[4], pb[2];
#pragma unroll
    for (int p = 0; p < 4; ++p)
        pa[p] = *reinterpret_cast<const f32x4*>(
            tokens + (size_t)(i0 + arw[p]) * Dm + ac4[p]);
#pragma unroll
    for (int p = 0; p < 2; ++p)
        pb[p] = *reinterpret_cast<const f32x4*>(
            tokens + (size_t)(j0 + brw[p]) * Dm + bc4[p]);

#pragma unroll 1
    for (int kp = 0; kp < Dm / KS; ++kp) {
        // Convert + LDS write (consumes pa/pb; prev iter's trailing barrier
        // ordered these writes after all prior LDS reads).
#pragma unroll
        for (int p = 0; p < 4; ++p) {
            u16x4 hi, lo;
#pragma unroll
            for (int e = 0; e < 4; ++e) {
                const unsigned short h = bf16rn(pa[p][e]);
                hi[e] = h;
                lo[e] = bf16rn(pa[p][e] - bf16tof(h));
            }
            *reinterpret_cast<u16x4*>(&Ah[arw[p] * LDH + ac4[p]]) = hi;
            *reinterpret_cast<u16x4*>(&Al[arw[p] * LDH + ac4[p]]) = lo;
        }
#pragma unroll
        for (int p = 0; p < 2; ++p) {
            u16x4 hi, lo;
#pragma unroll
            for (int e = 0; e < 4; ++e) {
                const unsigned short h = bf16rn(pb[p][e]);
                hi[e] = h;
                lo[e] = bf16rn(pb[p][e] - bf16tof(h));
            }
            *reinterpret_cast<u16x4*>(&Bh[brw[p] * LDH + bc4[p]]) = hi;
            *reinterpret_cast<u16x4*>(&Bl[brw[p] * LDH + bc4[p]]) = lo;
        }
        // Issue next kp's loads now: latency hides under barrier+frags+MFMA.
        if (kp < Dm / KS - 1) {
            const int kb = (kp + 1) * KS;
#pragma unroll
            for (int p = 0; p < 4; ++p)
                pa[p] = *reinterpret_cast<const f32x4*>(
                    tokens + (size_t)(i0 + arw[p]) * Dm + kb + ac4[p]);
#pragma unroll
            for (int p = 0; p < 2; ++p)
                pb[p] = *reinterpret_cast<const f32x4*>(
                    tokens + (size_t)(j0 + brw[p]) * Dm + kb + bc4[p]);
        }
        __syncthreads();

        // Fragments: lane lr = tile row/col, lk*8 = k offset (16B b128 reads).
        bf16x8 afh[4], afl[4], bfh[2], bfl[2];
#pragma unroll
        for (int rt = 0; rt < 4; ++rt) {
            const int row = (wr << 6) + (rt << 4) + lr;
            afh[rt] = *reinterpret_cast<const bf16x8*>(&Ah[row * LDH + (lk << 3)]);
            afl[rt] = *reinterpret_cast<const bf16x8*>(&Al[row * LDH + (lk << 3)]);
        }
#pragma unroll
        for (int ct = 0; ct < 2; ++ct) {
            const int col = (wc << 5) + (ct << 4) + lr;
            bfh[ct] = *reinterpret_cast<const bf16x8*>(&Bh[col * LDH + (lk << 3)]);
            bfl[ct] = *reinterpret_cast<const bf16x8*>(&Bl[col * LDH + (lk << 3)]);
        }
#pragma unroll
        for (int rt = 0; rt < 4; ++rt)
#pragma unroll
            for (int ct = 0; ct < 2; ++ct) {
                acc[rt][ct] = __builtin_amdgcn_mfma_f32_16x16x32_bf16(
                    afh[rt], bfh[ct], acc[rt][ct], 0, 0, 0);
                acc[rt][ct] = __builtin_amdgcn_mfma_f32_16x16x32_bf16(
                    afh[rt], bfl[ct], acc[rt][ct], 0, 0, 0);
                acc[rt][ct] = __builtin_amdgcn_mfma_f32_16x16x32_bf16(
                    afl[rt], bfh[ct], acc[rt][ct], 0, 0, 0);
            }
        __syncthreads();   // also makes staging LDS dead -> Ds reuse safe
    }

    const float e0 = edge_token[0];
    const float e1 = edge_token[1];
    const float e2 = edge_token[2];
    const float e3 = edge_token[3];

    float* __restrict__ adj  = out + (size_t)Tn * Dm;
    float* __restrict__ attr = adj + (size_t)Tn * Tn;

    // C/D layout (m89-verified): col = lane&15, row = (lane>>4)*4 + reg.
    // attr direct NT (256B contiguous per 4-store cluster); sim*m into Ds.
#pragma unroll
    for (int rt = 0; rt < 4; ++rt) {
#pragma unroll
        for (int ct = 0; ct < 2; ++ct) {
            const f32x4 dv = acc[rt][ct];
            const int jl = (wc << 5) + (ct << 4) + lr;
            const int j = j0 + jl;
#pragma unroll
            for (int reg = 0; reg < 4; ++reg) {
                const int il = (wr << 6) + (rt << 4) + (lk << 2) + reg;
                const float d = dv[reg];
                const float sim = __builtin_amdgcn_rcpf(1.0f + __expf(-d));
                const float m = (sim >= THRE) ? 1.0f : 0.0f;
                Ds[il * LDS_D + jl] = sim * m;
                f32x4 at;
                float v;
                v = d * e0; at.x = (v > 0.0f ? v : SLOPE * v) * m;
                v = d * e1; at.y = (v > 0.0f ? v : SLOPE * v) * m;
                v = d * e2; at.z = (v > 0.0f ? v : SLOPE * v) * m;
                v = d * e3; at.w = (v > 0.0f ? v : SLOPE * v) * m;
                __builtin_nontemporal_store(at,
                    reinterpret_cast<f32x4*>(attr + ((size_t)(i0 + il) * Tn + j) * En));
            }
        }
    }
    __syncthreads();

    // adj from Ds, row-major: per wave-instr 4 rows x 256B (2 full lines).
    const int c4 = lr << 2;
#pragma unroll
    for (int s = 0; s < 8; ++s) {
        const int row = (w << 5) + (s << 2) + lk;
        const f32x4 v = *reinterpret_cast<const f32x4*>(&Ds[row * LDS_D + c4]);
        __builtin_nontemporal_store(v,
            reinterpret_cast<f32x4*>(adj + (size_t)(i0 + row) * Tn + j0 + c4));
    }
}

extern "C" void kernel_launch(void* const* d_in, const int* in_sizes, int n_in,
                              void* d_out, int out_size, void* d_ws, size_t ws_size,
                              hipStream_t stream) {
    const float* tokens     = (const float*)d_in[0];  // [1,4096,128] f32
    const float* edge_token = (const float*)d_in[1];  // [1,4] f32
    float* out = (float*)d_out;

    hipLaunchKernelGGL(lp_fused, dim3(Tn / BN, Tn / BM), dim3(256), 0, stream,
                       tokens, edge_token, out);
}